// Round 1
// baseline (160.671 us; speedup 1.0000x reference)
//
#include <hip/hip_runtime.h>
#include <hip/hip_bf16.h>
#include <stdint.h>

#define B_ 64
#define N_ 1024
#define D_ 128

typedef __attribute__((ext_vector_type(8))) short bf16x8;
typedef __attribute__((ext_vector_type(4))) float f32x4;

__device__ __forceinline__ unsigned short f2bf(float f) {
    union { float f; uint32_t u; } v; v.f = f;
    uint32_t u = v.u;
    return (unsigned short)((u + 0x7FFFu + ((u >> 16) & 1u)) >> 16);
}

// ---------------------------------------------------------------------------
// Kernel 1: W (f32 [k=128][d=128]) -> bf16 W^T [d][k], for Wq/Wk/Wv.
// Tiny (3*64KB read), just get it done.
__global__ __launch_bounds__(256) void wtrans_kernel(
    const float* __restrict__ Wq, const float* __restrict__ Wk,
    const float* __restrict__ Wv, unsigned short* __restrict__ wt)
{
    int p = blockIdx.x >> 4;
    int seg = blockIdx.x & 15;
    const float* W = (p == 0) ? Wq : (p == 1) ? Wk : Wv;
    unsigned short* dst = wt + p * (D_ * D_);
    for (int i = 0; i < 4; ++i) {
        int idx = seg * 1024 + i * 256 + (int)threadIdx.x;
        int k = idx >> 7, d = idx & 127;
        dst[d * D_ + k] = f2bf(W[idx]);
    }
}

// ---------------------------------------------------------------------------
// Kernel 2: QKV projection. Each block: 64 rows of x. x staged once (bf16 LDS),
// then for each of Wq^T/Wk^T/Wv^T: stage W^T tile, MFMA 16x16x32, add bias,
// fold 1/sqrt(D) into q, store bf16 row-major [B*N][D].
__global__ __launch_bounds__(256) void proj_kernel(
    const float* __restrict__ x,
    const unsigned short* __restrict__ wtg,
    const float* __restrict__ bq, const float* __restrict__ bk,
    const float* __restrict__ bv,
    unsigned short* __restrict__ qo, unsigned short* __restrict__ ko,
    unsigned short* __restrict__ vo)
{
    __shared__ alignas(16) unsigned short xs[64 * 136];   // +8 pad
    __shared__ alignas(16) unsigned short ws[128 * 136];  // +8 pad
    const int tid = threadIdx.x;
    const int row0 = blockIdx.x * 64;

    // stage x tile f32->bf16 (coalesced float4 loads, 8B LDS writes)
    for (int it = 0; it < 8; ++it) {
        int idx4 = it * 256 + tid;          // 2048 float4 = 64x128
        int r = idx4 >> 5, c4 = (idx4 & 31) * 4;
        const float4 v = *(const float4*)&x[(size_t)(row0 + r) * D_ + c4];
        unsigned short tmp[4] = { f2bf(v.x), f2bf(v.y), f2bf(v.z), f2bf(v.w) };
        *(uint2*)&xs[r * 136 + c4] = *(uint2*)tmp;
    }

    const int wave = tid >> 6, lane = tid & 63;
    const int lr = lane & 15, lg = lane >> 4;
    const f32x4 zero4 = {0.f, 0.f, 0.f, 0.f};

    for (int p = 0; p < 3; ++p) {
        __syncthreads();   // xs ready (p=0) / prior ws reads done (p>0)
        const unsigned short* wsrc = wtg + p * (D_ * D_);
        for (int it = 0; it < 8; ++it) {
            int idx8 = it * 256 + tid;      // 2048 x 8 bf16 = 128x128
            int r = idx8 >> 4, c8 = (idx8 & 15) * 8;
            *(bf16x8*)&ws[r * 136 + c8] = *(const bf16x8*)&wsrc[idx8 * 8];
        }
        __syncthreads();

        // A-frags: 16 rows of x per wave, k contiguous per lane
        bf16x8 a[4];
        for (int kk = 0; kk < 4; ++kk)
            a[kk] = *(const bf16x8*)&xs[(wave * 16 + lr) * 136 + kk * 32 + lg * 8];
        f32x4 acc[8];
        for (int nt = 0; nt < 8; ++nt) acc[nt] = zero4;
        for (int kk = 0; kk < 4; ++kk)
            for (int nt = 0; nt < 8; ++nt) {
                bf16x8 bfr = *(const bf16x8*)&ws[(nt * 16 + lr) * 136 + kk * 32 + lg * 8];
                acc[nt] = __builtin_amdgcn_mfma_f32_16x16x32_bf16(a[kk], bfr, acc[nt], 0, 0, 0);
            }

        const float* bias = (p == 0) ? bq : (p == 1) ? bk : bv;
        unsigned short* outp = (p == 0) ? qo : (p == 1) ? ko : vo;
        const float sc = (p == 0) ? 0.08838834764831845f : 1.0f; // 1/sqrt(128) folded into q
        for (int nt = 0; nt < 8; ++nt) {
            int d = nt * 16 + lr;
            float bb = bias[d];
            for (int r = 0; r < 4; ++r) {
                int grow = row0 + wave * 16 + lg * 4 + r;  // C/D: row=(lane>>4)*4+reg
                outp[(size_t)grow * D_ + d] = f2bf((acc[nt][r] + bb) * sc);
            }
        }
    }
}

// ---------------------------------------------------------------------------
// Kernel 3: flash attention. grid(B, N/64): batch on x so blockid%8==b%8
// (same-batch q-tiles share an XCD's L2 for K/V). 4 waves x 16 q-rows.
__global__ __launch_bounds__(256) void attn_kernel(
    const unsigned short* __restrict__ qg, const unsigned short* __restrict__ kg,
    const unsigned short* __restrict__ vg, const int* __restrict__ valid_lens,
    float* __restrict__ out)
{
    __shared__ alignas(16) unsigned short ks[64 * 136];   // K tile row-major, +8 pad
    __shared__ alignas(16) unsigned short vt[128 * 72];   // V^T tile [d][kv], +8 pad
    __shared__ alignas(16) unsigned short ps[4 * 16 * 72]; // per-wave P tile

    const int b = blockIdx.x, qt = blockIdx.y;
    const int q0 = qt * 64;
    const int L = valid_lens[b];
    const int tid = threadIdx.x;
    float* outb = out + (size_t)b * N_ * D_;

    if (q0 >= L) {  // whole tile is masked rows -> zeros
        for (int it = 0; it < 8; ++it) {
            int idx4 = it * 256 + tid;
            int r = idx4 >> 5, c4 = (idx4 & 31) * 4;
            float4 z; z.x = z.y = z.z = z.w = 0.f;
            *(float4*)&outb[(size_t)(q0 + r) * D_ + c4] = z;
        }
        return;
    }

    const int wave = tid >> 6, lane = tid & 63;
    const int lr = lane & 15, lg = lane >> 4;
    const f32x4 zero4 = {0.f, 0.f, 0.f, 0.f};

    // Q fragments (scale already folded in at projection)
    bf16x8 aq[4];
    {
        const unsigned short* qrow = qg + (size_t)(b * N_ + q0 + wave * 16 + lr) * D_;
        for (int kk = 0; kk < 4; ++kk)
            aq[kk] = *(const bf16x8*)&qrow[kk * 32 + lg * 8];
    }

    f32x4 oacc[8];
    for (int i = 0; i < 8; ++i) oacc[i] = zero4;
    float mrun[4], lrun[4];
    for (int r = 0; r < 4; ++r) { mrun[r] = -1e30f; lrun[r] = 0.f; }

    const int ntiles = (L + 63) >> 6;
    for (int t = 0; t < ntiles; ++t) {
        const int kv0 = t * 64;
        __syncthreads();  // previous tile's LDS reads done
        // stage K tile (fully coalesced 16B, conflict-free b128 LDS writes)
        for (int it = 0; it < 4; ++it) {
            int idx8 = it * 256 + tid;
            int r = idx8 >> 4, c8 = (idx8 & 15) * 8;
            *(bf16x8*)&ks[r * 136 + c8] =
                *(const bf16x8*)&kg[(size_t)(b * N_ + kv0 + r) * D_ + c8];
        }
        // stage V^T: lane=kv so each ds_write_u16 hits contiguous 128B (no conflicts)
        {
            int kv = tid & 63, dq = (tid >> 6) * 8;
            for (int it = 0; it < 4; ++it) {
                int dbase = dq + it * 32;
                bf16x8 vv = *(const bf16x8*)&vg[(size_t)(b * N_ + kv0 + kv) * D_ + dbase];
                for (int j = 0; j < 8; ++j)
                    vt[(dbase + j) * 72 + kv] = ((unsigned short*)&vv)[j];
            }
        }
        __syncthreads();

        // S = Q K^T : 4 kv-subtiles of 16, K-loop over d
        f32x4 s[4];
        for (int nt = 0; nt < 4; ++nt) {
            s[nt] = zero4;
            for (int kk = 0; kk < 4; ++kk) {
                bf16x8 bk_ = *(const bf16x8*)&ks[(nt * 16 + lr) * 136 + kk * 32 + lg * 8];
                s[nt] = __builtin_amdgcn_mfma_f32_16x16x32_bf16(aq[kk], bk_, s[nt], 0, 0, 0);
            }
        }
        // column mask (j >= L)
        for (int nt = 0; nt < 4; ++nt) {
            int j = kv0 + nt * 16 + lr;
            if (j >= L) for (int r = 0; r < 4; ++r) s[nt][r] = -1e30f;
        }
        // online softmax: row = lg*4+r lives in the 16-lane group
        float pm[4];
        for (int r = 0; r < 4; ++r)
            pm[r] = fmaxf(fmaxf(s[0][r], s[1][r]), fmaxf(s[2][r], s[3][r]));
        for (int off = 1; off < 16; off <<= 1)
            for (int r = 0; r < 4; ++r)
                pm[r] = fmaxf(pm[r], __shfl_xor(pm[r], off));
        float alpha[4];
        for (int r = 0; r < 4; ++r) {
            float mn = fmaxf(mrun[r], pm[r]);
            alpha[r] = __expf(mrun[r] - mn);
            mrun[r] = mn;
        }
        float p[4][4], rs[4];
        for (int r = 0; r < 4; ++r) rs[r] = 0.f;
        for (int nt = 0; nt < 4; ++nt)
            for (int r = 0; r < 4; ++r) {
                float e = __expf(s[nt][r] - mrun[r]);
                p[nt][r] = e;
                rs[r] += e;
            }
        for (int off = 1; off < 16; off <<= 1)
            for (int r = 0; r < 4; ++r)
                rs[r] += __shfl_xor(rs[r], off);
        for (int r = 0; r < 4; ++r) lrun[r] = lrun[r] * alpha[r] + rs[r];
        for (int nt = 0; nt < 8; ++nt)
            for (int r = 0; r < 4; ++r)
                oacc[nt][r] *= alpha[r];

        // P -> wave-private LDS (bf16), then consume as MFMA A-frags.
        // Same-wave LDS RAW: in-order per wave; same-array alias keeps compiler honest.
        unsigned short* pw = ps + wave * (16 * 72);
        for (int nt = 0; nt < 4; ++nt)
            for (int r = 0; r < 4; ++r)
                pw[(lg * 4 + r) * 72 + nt * 16 + lr] = f2bf(p[nt][r]);

        // O += P V
        for (int kk = 0; kk < 2; ++kk) {
            bf16x8 ap = *(const bf16x8*)&pw[lr * 72 + kk * 32 + lg * 8];
            for (int nt = 0; nt < 8; ++nt) {
                bf16x8 bv_ = *(const bf16x8*)&vt[(nt * 16 + lr) * 72 + kk * 32 + lg * 8];
                oacc[nt] = __builtin_amdgcn_mfma_f32_16x16x32_bf16(ap, bv_, oacc[nt], 0, 0, 0);
            }
        }
    }

    // epilogue: divide by l, zero rows >= L
    for (int r = 0; r < 4; ++r) {
        int qrow = q0 + wave * 16 + lg * 4 + r;
        float inv = (qrow < L) ? 1.0f / lrun[r] : 0.0f;
        for (int nt = 0; nt < 8; ++nt) {
            int d = nt * 16 + lr;
            outb[(size_t)qrow * D_ + d] = oacc[nt][r] * inv;
        }
    }
}

// ---------------------------------------------------------------------------
extern "C" void kernel_launch(void* const* d_in, const int* in_sizes, int n_in,
                              void* d_out, int out_size, void* d_ws, size_t ws_size,
                              hipStream_t stream) {
    const float* x    = (const float*)d_in[0];
    const int*   vlen = (const int*)d_in[1];
    const float* Wq   = (const float*)d_in[2];
    const float* bq   = (const float*)d_in[3];
    const float* Wk   = (const float*)d_in[4];
    const float* bk   = (const float*)d_in[5];
    const float* Wv   = (const float*)d_in[6];
    const float* bv   = (const float*)d_in[7];
    float* out = (float*)d_out;

    // ws layout: [W^T bf16 x3 | q bf16 | k bf16 | v bf16]
    unsigned short* wt  = (unsigned short*)d_ws;                  // 3*128*128
    unsigned short* qws = (unsigned short*)((char*)d_ws + 98304);
    unsigned short* kws = qws + (size_t)B_ * N_ * D_;
    unsigned short* vws = kws + (size_t)B_ * N_ * D_;

    wtrans_kernel<<<48, 256, 0, stream>>>(Wq, Wk, Wv, wt);
    proj_kernel<<<(B_ * N_) / 64, 256, 0, stream>>>(x, wt, bq, bk, bv, qws, kws, vws);
    attn_kernel<<<dim3(B_, N_ / 64), 256, 0, stream>>>(qws, kws, vws, vlen, out);
}